// Round 8
// baseline (81.559 us; speedup 1.0000x reference)
//
#include <hip/hip_runtime.h>
#include <cstddef>

#define EPS 1e-6f
constexpr float INV_SQRT_E = 0.6065306597126334f;  // exp(-0.5*THETA^2), THETA=1

// Fused, all 4 dilations, tile 64x16, block (64,8): each thread computes a
// PAIR of output rows (ra, ra+D). The SAD tap rows of the pair overlap in
// KS-1 of KS rows per column tap -> shared walk reads KS+1 rows for 2 pixels
// (45 vs 81 reads/px at D=4). Row pairing: g=ty/D, ra=2*D*g+(ty-g*D);
// partitions rows 0..15 exactly for D in {1,2,4}; D=3 leftover pair {13,14}
// does two independent walks (wave-uniform branch, ty == wave id).
// Pass-1 separable vertical-first; column sums packed float4 -> one
// ds_read_b128 per tap. LDS max 61440 B (D=4) -> 2 blocks/CU.
template <int D>
__device__ __forceinline__ void body(const float* __restrict__ x,
                                     float* __restrict__ out,
                                     char* smem, int bc, int H, int W)
{
    constexpr int PAD = D * D;          // halo per side
    constexpr int KS  = 2 * D + 1;      // taps per axis
    constexpr int K   = KS * KS;        // patch size
    constexpr int TW  = 64, TH = 16;
    constexpr int LW  = TW + 2 * PAD;
    constexpr int LH  = TH + 2 * PAD;
    constexpr float INVK = 1.0f / (float)K;
    constexpr float UNB  = (float)K / (float)(K - 1);

    float2* sv = (float2*)smem;                    // {v, v*log(v+eps)}
    float4* cs = (float4*)(smem + LH * LW * 8);    // {col_s, col_s2, col_sl, -}

    const int w0 = blockIdx.x * TW;
    const int h0 = blockIdx.y * TH;
    const float* xp = x + (size_t)bc * H * W;
    const int tid = threadIdx.y * 64 + threadIdx.x;

    // Staging: tile + halo, zeros outside the image.
    for (int idx = tid; idx < LH * LW; idx += 512) {
        const int r  = idx / LW;
        const int cc = idx - r * LW;
        const int gh = h0 - PAD + r;
        const int gw = w0 - PAD + cc;
        float v = 0.0f;
        if (gh >= 0 && gh < H && gw >= 0 && gw < W) v = xp[gh * W + gw];
        sv[idx] = make_float2(v, v * __logf(v + EPS));  // v=0 -> exactly 0
    }
    __syncthreads();

    // Vertical stage: column sums over KS row taps, TH x LW plane.
    for (int e = tid; e < TH * LW; e += 512) {
        const int r = e / LW;
        const int c = e - r * LW;
        const float2* cp = &sv[r * LW + c];
        float vs = 0.0f, vs2 = 0.0f, vsl = 0.0f;
        #pragma unroll
        for (int mi = 0; mi < KS; ++mi) {
            const float2 p = cp[(mi * D) * LW];
            vs  += p.x;
            vs2  = fmaf(p.x, p.x, vs2);
            vsl += p.y;
        }
        cs[e] = make_float4(vs, vs2, vsl, 0.0f);
    }
    __syncthreads();

    const int tx = threadIdx.x, ty = threadIdx.y;

    // Row pair for this thread.
    int g = ty / D, u = ty - g * D;
    int ra = 2 * D * g + u, rb = ra + D;
    bool shared_pair = true;
    if constexpr (D == 3) {
        if (ty == 7) { ra = 13; rb = 14; shared_pair = false; }
    }

    // Horizontal stage: KS float4 taps per row.
    float sa = 0, s2a = 0, sla = 0, sb = 0, s2b = 0, slb = 0;
    {
        const float4* qa = &cs[ra * LW + tx];
        const float4* qb = &cs[rb * LW + tx];
        #pragma unroll
        for (int mj = 0; mj < KS; ++mj) {
            const float4 A = qa[mj * D];
            const float4 B = qb[mj * D];
            sa += A.x; s2a += A.y; sla += A.z;
            sb += B.x; s2b += B.y; slb += B.z;
        }
    }
    const float mua = sa * INVK, mub = sb * INVK;

    // SAD: shared walk of KS+1 tap rows serves both pixels.
    float sada = 0.0f, sadb = 0.0f;
    const float2* basea = &sv[ra * LW + tx];
    if (shared_pair) {     // constexpr-true except D=3,ty=7 (wave-uniform)
        #pragma unroll
        for (int mj = 0; mj < KS; ++mj) {
            #pragma unroll
            for (int t = 0; t <= KS; ++t) {
                const float v = basea[(t * D) * LW + mj * D].x;
                if (t < KS)  sada += fabsf(v - mua);
                if (t >= 1)  sadb += fabsf(v - mub);
            }
        }
    } else {
        const float2* baseb = &sv[rb * LW + tx];
        #pragma unroll
        for (int mi = 0; mi < KS; ++mi)
            #pragma unroll
            for (int mj = 0; mj < KS; ++mj) {
                sada += fabsf(basea[(mi * D) * LW + mj * D].x - mua);
                sadb += fabsf(baseb[(mi * D) * LW + mj * D].x - mub);
            }
    }

    // Epilogue for both rows.
    const size_t fstride = (size_t)H * W;
    float* op = out + (size_t)bc * 4 * fstride + w0 + tx;
    #pragma unroll
    for (int half = 0; half < 2; ++half) {
        const int   r   = half ? rb : ra;
        const float s   = half ? sb : sa;
        const float s2  = half ? s2b : s2a;
        const float sl  = half ? slb : sla;
        const float sad = half ? sadb : sada;

        const float mu       = s * INVK;
        const float energy   = s2 * INVK;
        const float var      = fmaxf(energy - mu * mu, 0.0f);
        const float sd       = sqrtf(var * UNB) + EPS;
        const float contrast = var / (sd * sd);
        const float entropy  = -sl * INVK;
        const float homog    = 1.0f / (1.0f + sad * INVK);

        const size_t rowoff = (size_t)(h0 + r) * W;
        __builtin_nontemporal_store((contrast + EPS) * INV_SQRT_E, &op[0 * fstride + rowoff]);
        __builtin_nontemporal_store((energy   + EPS) * INV_SQRT_E, &op[1 * fstride + rowoff]);
        __builtin_nontemporal_store((entropy  + EPS) * INV_SQRT_E, &op[2 * fstride + rowoff]);
        __builtin_nontemporal_store((homog    + EPS) * INV_SQRT_E, &op[3 * fstride + rowoff]);
    }
}

__global__ __launch_bounds__(512, 4) void tex_fused(
    const float* __restrict__ x, float* __restrict__ out, int H, int W)
{
    extern __shared__ char smem[];
    const int dz = blockIdx.z >> 3;      // 0..3, heavy-first: 0->D4 ... 3->D1
    const int bc = blockIdx.z & 7;       // b*C + c
    const size_t per = (size_t)8 * 4 * H * W;
    switch (dz) {
        case 0: body<4>(x, out + 3 * per, smem, bc, H, W); break;
        case 1: body<3>(x, out + 2 * per, smem, bc, H, W); break;
        case 2: body<2>(x, out + 1 * per, smem, bc, H, W); break;
        default: body<1>(x, out + 0 * per, smem, bc, H, W); break;
    }
}

extern "C" void kernel_launch(void* const* d_in, const int* in_sizes, int n_in,
                              void* d_out, int out_size, void* d_ws, size_t ws_size,
                              hipStream_t stream) {
    const float* x = (const float*)d_in[0];
    float* out = (float*)d_out;

    const int H = 256, W = 256;
    // Per-D LDS (TH=16, PAD=D*D): sv LH*LW*8 + cs TH*LW*16
    //   D=4: LH=48, LW=96: 36864 + 24576 = 61440  (max, < 64 KB)
    //   D=3: LH=34, LW=82: 22304 + 20992 = 43296
    //   D=2: LH=24, LW=72: 13824 + 18432 = 32256
    //   D=1: LH=18, LW=66:  9504 + 16896 = 26400
    const size_t smem_bytes = 61440;

    dim3 blk(64, 8, 1);
    dim3 grd(W / 64, H / 16, 8 * 4);     // 4 x-tiles, 16 y-tiles, (bc x dz)
    tex_fused<<<grd, blk, smem_bytes, stream>>>(x, out, H, W);
}

// Round 9
// 79.876 us; speedup vs baseline: 1.0211x; 1.0211x over previous
//
#include <hip/hip_runtime.h>
#include <cstddef>

#define EPS 1e-6f
constexpr float INV_SQRT_E = 0.6065306597126334f;  // exp(-0.5*THETA^2), THETA=1

// R7 structure (best: 79.7 us) + latency fixes:
//  - staging loads batched: constexpr-trip unrolled load loop into registers,
//    then write loop -> one vmcnt drain instead of NI serialized round trips.
//  - dilations interleaved in z (dz = z&3) so each CU's 4 co-resident blocks
//    mix cheap/heavy bodies instead of phase-homogeneous stampedes.
// Tile 64x8, block (64,8)=8 waves, LDS max 39936 B -> 4 blocks/CU = 32 waves.
// Pass-1 separable vertical-first (col sums in LDS); SAD K-tap (mu per-pixel).
template <int D>
__device__ __forceinline__ void body(const float* __restrict__ x,
                                     float* __restrict__ out,
                                     char* smem, int bc, int H, int W)
{
    constexpr int PAD = D * D;          // halo per side
    constexpr int KS  = 2 * D + 1;      // taps per axis
    constexpr int K   = KS * KS;        // patch size
    constexpr int TW  = 64, TH = 8;
    constexpr int LW  = TW + 2 * PAD;
    constexpr int LH  = TH + 2 * PAD;
    constexpr int NE  = LH * LW;                 // staged elements
    constexpr int NI  = (NE + 511) / 512;        // staging iters (<=8)
    constexpr float INVK = 1.0f / (float)K;
    constexpr float UNB  = (float)K / (float)(K - 1);

    float2* sv  = (float2*)smem;                          // {v, v*log(v+eps)}
    float2* cs2 = (float2*)(smem + LH * LW * 8);          // {col_s, col_s2}
    float*  cs1 = (float*) (smem + LH * LW * 8 + TH * LW * 8);  // col_sl

    const int w0 = blockIdx.x * TW;
    const int h0 = blockIdx.y * TH;
    const float* xp = x + (size_t)bc * H * W;
    const int tid = threadIdx.y * 64 + threadIdx.x;

    // ---- Staging, two-phase: all loads in flight, then LDS writes. ----
    float vb[NI];
    #pragma unroll
    for (int i = 0; i < NI; ++i) {
        const int idx = tid + i * 512;
        float v = 0.0f;
        if (idx < NE) {
            const int r  = idx / LW;
            const int cc = idx - r * LW;
            const int gh = h0 - PAD + r;
            const int gw = w0 - PAD + cc;
            if (gh >= 0 && gh < H && gw >= 0 && gw < W) v = xp[gh * W + gw];
        }
        vb[i] = v;
    }
    #pragma unroll
    for (int i = 0; i < NI; ++i) {
        const int idx = tid + i * 512;
        if (idx < NE)
            sv[idx] = make_float2(vb[i], vb[i] * __logf(vb[i] + EPS));
    }
    __syncthreads();

    const int tx = threadIdx.x;
    const int ty = threadIdx.y;

    float s = 0.0f, s2 = 0.0f, sl = 0.0f;
    float sad;

    if constexpr (K <= 9) {
        // D=1: single pass, taps cached in registers.
        const float2* base = &sv[ty * LW + tx];
        float ta[K];
        #pragma unroll
        for (int mi = 0; mi < KS; ++mi)
            #pragma unroll
            for (int mj = 0; mj < KS; ++mj) {
                const float2 p = base[(mi * D) * LW + mj * D];
                ta[mi * KS + mj] = p.x;
                s  += p.x;
                s2  = fmaf(p.x, p.x, s2);
                sl += p.y;
            }
        const float mu = s * INVK;
        sad = 0.0f;
        #pragma unroll
        for (int i = 0; i < K; ++i) sad += fabsf(ta[i] - mu);
    } else {
        // Vertical stage: column sums over KS row taps, TH x LW plane.
        constexpr int NC = TH * LW;
        for (int e = tid; e < NC; e += 512) {
            const int r = e / LW;
            const int c = e - r * LW;
            const float2* cp = &sv[r * LW + c];
            float vs = 0.0f, vs2 = 0.0f, vsl = 0.0f;
            #pragma unroll
            for (int mi = 0; mi < KS; ++mi) {
                const float2 p = cp[(mi * D) * LW];
                vs  += p.x;
                vs2  = fmaf(p.x, p.x, vs2);
                vsl += p.y;
            }
            cs2[e] = make_float2(vs, vs2);
            cs1[e] = vsl;
        }
        __syncthreads();

        // Horizontal stage: KS taps over column sums.
        const float2* q2 = &cs2[ty * LW + tx];
        const float*  q1 = &cs1[ty * LW + tx];
        #pragma unroll
        for (int mj = 0; mj < KS; ++mj) {
            const float2 q = q2[mj * D];
            s  += q.x;
            s2 += q.y;
            sl += q1[mj * D];
        }
        const float mu = s * INVK;

        // SAD pass: K taps (mu per-pixel; not separable).
        const float2* base = &sv[ty * LW + tx];
        sad = 0.0f;
        #pragma unroll
        for (int mi = 0; mi < KS; ++mi)
            #pragma unroll
            for (int mj = 0; mj < KS; ++mj)
                sad += fabsf(base[(mi * D) * LW + mj * D].x - mu);
    }

    const float mu       = s * INVK;
    const float energy   = s2 * INVK;
    const float var      = fmaxf(energy - mu * mu, 0.0f);
    const float sd       = sqrtf(var * UNB) + EPS;
    const float contrast = var / (sd * sd);
    const float entropy  = -sl * INVK;
    const float homog    = 1.0f / (1.0f + sad * INVK);

    const size_t fstride = (size_t)H * W;
    const size_t rowoff  = (size_t)(h0 + ty) * W;
    float* op = out + (size_t)bc * 4 * fstride + w0 + tx;
    __builtin_nontemporal_store((contrast + EPS) * INV_SQRT_E, &op[0 * fstride + rowoff]);
    __builtin_nontemporal_store((energy   + EPS) * INV_SQRT_E, &op[1 * fstride + rowoff]);
    __builtin_nontemporal_store((entropy  + EPS) * INV_SQRT_E, &op[2 * fstride + rowoff]);
    __builtin_nontemporal_store((homog    + EPS) * INV_SQRT_E, &op[3 * fstride + rowoff]);
}

__global__ __launch_bounds__(512, 8) void tex_fused(
    const float* __restrict__ x, float* __restrict__ out, int H, int W)
{
    extern __shared__ char smem[];
    const int dz = blockIdx.z & 3;       // dilation in FAST bits: co-resident
    const int bc = blockIdx.z >> 2;      // blocks on a CU mix D1..D4
    const size_t per = (size_t)8 * 4 * H * W;
    switch (dz) {
        case 0: body<4>(x, out + 3 * per, smem, bc, H, W); break;
        case 1: body<3>(x, out + 2 * per, smem, bc, H, W); break;
        case 2: body<2>(x, out + 1 * per, smem, bc, H, W); break;
        default: body<1>(x, out + 0 * per, smem, bc, H, W); break;
    }
}

extern "C" void kernel_launch(void* const* d_in, const int* in_sizes, int n_in,
                              void* d_out, int out_size, void* d_ws, size_t ws_size,
                              hipStream_t stream) {
    const float* x = (const float*)d_in[0];
    float* out = (float*)d_out;

    const int H = 256, W = 256;
    // Per-D LDS (TH=8, PAD=D*D): sv LH*LW*8 + cs TH*LW*12
    //   D=4: LH=40, LW=96: 30720 + 9216 = 39936  (max) -> 4 blocks/CU
    //   D=3: LH=26, LW=82: 17056 + 7872 = 24928
    //   D=2: LH=16, LW=72:  9216 + 6912 = 16128
    //   D=1: LH=10, LW=66:  5280 (register path)
    const size_t smem_bytes = 39936;

    dim3 blk(64, 8, 1);
    dim3 grd(W / 64, H / 8, 8 * 4);      // 4 x-tiles, 32 y-tiles, (bc x dz)
    tex_fused<<<grd, blk, smem_bytes, stream>>>(x, out, H, W);
}